// Round 5
// baseline (317.267 us; speedup 1.0000x reference)
//
#include <hip/hip_runtime.h>

// CVRP decoder v5, MI355X. 4 kernels:
//  K0 prep_w: Wkv/Wq/Wc^T -> bf16 swizzled (+ wq_last col)
//  K1 fused_proj (roles): kv-GEMM | q-GEMM | nodesC-GEMM (nodes@Wc) | bias_n
//     A-operands converted fp32->bf16 inline (no convert kernel).
//  K2 attn (32x32 MFMA, register P-relayout)
//  K3 s2: score2 = O @ nodes_c^T (+bias_n) fused with topk/tanh/softmax,
//     XCD-affinity block swizzle.
// Swizzle: (row,k): granule g=k>>3 stored at pos=(g&~7)|((g&7)^(row&7)).

typedef unsigned short u16;
typedef unsigned int u32;
typedef unsigned long long u64;
typedef __attribute__((ext_vector_type(8))) short short8;
typedef __attribute__((ext_vector_type(4))) float f32x4;
typedef __attribute__((ext_vector_type(16))) float f32x16;
typedef __attribute__((ext_vector_type(4))) u32 u32x4;
typedef __attribute__((ext_vector_type(8))) u16 u16x8;

#define AS1U(p) ((const __attribute__((address_space(1))) u32*)(p))
#define AS3U(p) ((__attribute__((address_space(3))) u32*)(p))

#define QSCALE (0.25f * 1.44269504088896340736f)  // 1/sqrt(D) * log2(e)
#define LOG2E 1.44269504088896340736f
#define INV_SQRT2 0.70710678118654752440f

__device__ __forceinline__ u16 f2bf(float f) {
  u32 u = __builtin_bit_cast(u32, f);
  return (u16)((u + 0x7FFFu + ((u >> 16) & 1u)) >> 16);  // RNE
}

__device__ __forceinline__ u32 pack_bf(float a, float b) {
  u32 ua = __builtin_bit_cast(u32, a), ub = __builtin_bit_cast(u32, b);
  ua = ua + 0x7FFFu + ((ua >> 16) & 1u);
  ub = ub + 0x7FFFu + ((ub >> 16) & 1u);
  return __builtin_amdgcn_perm(ub, ua, 0x07060302u);
}

__device__ __forceinline__ short8 packf8(float4 a, float4 b) {
  u32x4 r = {pack_bf(a.x, a.y), pack_bf(a.z, a.w),
             pack_bf(b.x, b.y), pack_bf(b.z, b.w)};
  return __builtin_bit_cast(short8, r);
}

__device__ __forceinline__ u32 swz_off(u32 row, u32 k) {  // half-index
  u32 g = k >> 3;
  u32 pos = (g & ~7u) | ((g & 7u) ^ (row & 7u));
  return row * 256u + pos * 8u + (k & 7u);
}

__device__ __forceinline__ float fast_tanh(float x) {
  float e = __builtin_amdgcn_exp2f(x * (2.0f * LOG2E));
  return 1.0f - 2.0f * __builtin_amdgcn_rcpf(e + 1.0f);
}

// ---------------------------------------------------------------------------
// K0: weight prep. Wkv (512x256), Wq main (256x256, src stride 257),
// Wc^T (256x256 gather-transpose), wq_last column. All bf16 swizzled rows.
// ---------------------------------------------------------------------------
__global__ __launch_bounds__(256) void prep_w_kernel(
    const float* __restrict__ Wk, const float* __restrict__ Wv,
    const float* __restrict__ Wq, const float* __restrict__ Wc,
    u16* __restrict__ Wkv_bf, u16* __restrict__ Wq_bf,
    u16* __restrict__ WcT_bf, float* __restrict__ wq_last) {
  int i = blockIdx.x * 256 + threadIdx.x;
  if (i < 16384) {  // Wkv
    u32 row = (u32)i >> 5, g = (u32)i & 31;
    const float* src = (row < 256) ? (Wk + row * 256 + g * 8)
                                   : (Wv + (row - 256) * 256 + g * 8);
    u16x8 o;
    for (int q = 0; q < 8; ++q) o[q] = f2bf(src[q]);
    u32 pos = (g & ~7u) | ((g & 7u) ^ (row & 7u));
    *(u16x8*)(Wkv_bf + row * 256 + pos * 8) = o;
  } else if (i < 24576) {  // Wq main
    int j = i - 16384;
    u32 row = (u32)j >> 5, g = (u32)j & 31;
    const float* src = Wq + row * 257 + g * 8;
    u16x8 o;
    for (int q = 0; q < 8; ++q) o[q] = f2bf(src[q]);
    u32 pos = (g & ~7u) | ((g & 7u) ^ (row & 7u));
    *(u16x8*)(Wq_bf + row * 256 + pos * 8) = o;
  } else if (i < 32768) {  // Wc^T: W'[j][i] = Wc[i][j]
    int j = i - 24576;
    u32 row = (u32)j >> 5, g = (u32)j & 31;  // row = output col j
    u16x8 o;
    for (int q = 0; q < 8; ++q) o[q] = f2bf(Wc[(g * 8 + q) * 256 + row]);
    u32 pos = (g & ~7u) | ((g & 7u) ^ (row & 7u));
    *(u16x8*)(WcT_bf + row * 256 + pos * 8) = o;
  } else if (i < 33024) {  // Wq last column (fp32)
    int o = i - 32768;
    wq_last[o] = Wq[o * 257 + 256];
  }
}

// ---------------------------------------------------------------------------
// proj core (fp32 A): block = 64m x 64j, K=256. A-frags built inline from
// fp32 (2x float4 load + pack per frag), W (bf16 swizzled) DMA-staged once,
// single barrier, pure ds_read+MFMA K-loop. Wave (2x2): 32m x 32j.
// ---------------------------------------------------------------------------
__device__ __forceinline__ void proj_core_f32(
    const float* __restrict__ Abase, const u16* __restrict__ Wswz,
    u16* Ws, f32x4 acc[2][2]) {
  const int t = threadIdx.x;
  const int lane = t & 63, w = t >> 6;
  const int wm = (w & 1) * 32, wj = (w >> 1) * 32;
  const int qq = lane >> 4, lr = lane & 15;
#pragma unroll
  for (int c = 0; c < 8; ++c)
    __builtin_amdgcn_global_load_lds(AS1U(Wswz + c * 2048 + t * 8),
                                     AS3U(Ws + c * 2048 + w * 512), 16, 0, 0);
  short8 af[2][8];
#pragma unroll
  for (int kt = 0; kt < 8; ++kt) {
    int g = kt * 4 + qq;
#pragma unroll
    for (int ms = 0; ms < 2; ++ms) {
      const float4* p = (const float4*)(Abase + (wm + ms * 16 + lr) * 256 + g * 8);
      af[ms][kt] = packf8(p[0], p[1]);
    }
  }
  acc[0][0] = (f32x4){0.f, 0.f, 0.f, 0.f};
  acc[0][1] = (f32x4){0.f, 0.f, 0.f, 0.f};
  acc[1][0] = (f32x4){0.f, 0.f, 0.f, 0.f};
  acc[1][1] = (f32x4){0.f, 0.f, 0.f, 0.f};
  __syncthreads();
#pragma unroll
  for (int kt = 0; kt < 8; ++kt) {
    int g = kt * 4 + qq;
    int pos = (g & ~7) | ((g & 7) ^ (lr & 7));
    short8 b0 = *(const short8*)(Ws + (wj + lr) * 256 + pos * 8);
    short8 b1 = *(const short8*)(Ws + (wj + 16 + lr) * 256 + pos * 8);
    acc[0][0] = __builtin_amdgcn_mfma_f32_16x16x32_bf16(af[0][kt], b0, acc[0][0], 0, 0, 0);
    acc[0][1] = __builtin_amdgcn_mfma_f32_16x16x32_bf16(af[0][kt], b1, acc[0][1], 0, 0, 0);
    acc[1][0] = __builtin_amdgcn_mfma_f32_16x16x32_bf16(af[1][kt], b0, acc[1][0], 0, 0, 0);
    acc[1][1] = __builtin_amdgcn_mfma_f32_16x16x32_bf16(af[1][kt], b1, acc[1][1], 0, 0, 0);
  }
}

// ---------------------------------------------------------------------------
// K1: fused projections. Roles by blockIdx:
//   [0,2048)    kv:  A=nodes fp32, W=Wkv_bf   -> Kbuf/Vbuf (attn layouts)
//   [2048,3072) q:   A=last fp32,  W=Wq_bf    -> Qbuf (+load*wq_last, *QSCALE)
//   [3072,4096) nC:  A=nodes fp32, W=WcT_bf   -> nodes_c (swizzled bf16)
//   [4096,4128) bias: bias_n[b][n] = <Wc_b, nodes[b][n]>
// ---------------------------------------------------------------------------
__global__ __launch_bounds__(256) void fused_proj_kernel(
    const float* __restrict__ nodes, const float* __restrict__ last,
    const float* __restrict__ loadv, const float* __restrict__ Wcb,
    const u16* __restrict__ Wkv_bf, const u16* __restrict__ Wq_bf,
    const u16* __restrict__ WcT_bf, const float* __restrict__ wq_last,
    u16* __restrict__ Kbuf, u16* __restrict__ Vbuf, u16* __restrict__ Qbuf,
    u16* __restrict__ nodes_c, float* __restrict__ bias_n) {
  __shared__ __attribute__((aligned(16))) u16 Ws[16384];
  int bx = blockIdx.x;
  int t = threadIdx.x, lane = t & 63, w = t >> 6;
  int wm = (w & 1) * 32, wj = (w >> 1) * 32, qq = lane >> 4, lr = lane & 15;
  if (bx < 2048) {  // ---- kv role
    int jt = bx & 7, mt = (bx >> 3) & 7, b = bx >> 6;
    f32x4 acc[2][2];
    proj_core_f32(nodes + ((long)b * 512 + mt * 64) * 256, Wkv_bf + jt * 64 * 256, Ws, acc);
    for (int ms = 0; ms < 2; ++ms)
      for (int fj = 0; fj < 2; ++fj) {
        int j = jt * 64 + wj + fj * 16 + lr;
        for (int r = 0; r < 4; ++r) {
          int n = mt * 64 + wm + ms * 16 + qq * 4 + r;
          u16 val = f2bf(acc[ms][fj][r]);
          if (j < 256) {  // K: [bh][nch32][2][32][8]
            int h = j >> 4, d = j & 15;
            Kbuf[(u32)(b * 16 + h) * 8192 + (u32)(n >> 5) * 512 +
                 (u32)(d >> 3) * 256 + (u32)(n & 31) * 8 + (u32)(d & 7)] = val;
          } else {        // V: [bh][d][n] swizzled on n
            int o = j - 256, h = o >> 4, d = o & 15;
            u32 G = (u32)(n >> 3);
            u32 pos = (G & ~7u) | ((G & 7u) ^ ((u32)d & 7u));
            Vbuf[(u32)(b * 16 + h) * 8192 + (u32)d * 512 + pos * 8 + (u32)(n & 7)] = val;
          }
        }
      }
  } else if (bx < 3072) {  // ---- q role
    int ix = bx - 2048;
    int jt = ix & 3, mt = (ix >> 2) & 7, b = ix >> 5;
    f32x4 acc[2][2];
    proj_core_f32(last + ((long)b * 512 + mt * 64) * 256, Wq_bf + jt * 64 * 256, Ws, acc);
    for (int ms = 0; ms < 2; ++ms)
      for (int fj = 0; fj < 2; ++fj) {
        int o = jt * 64 + wj + fj * 16 + lr;
        float wql = wq_last[o];
        for (int r = 0; r < 4; ++r) {
          int p = mt * 64 + wm + ms * 16 + qq * 4 + r;
          float ld = loadv[b * 512 + p];
          float v = (acc[ms][fj][r] + ld * wql) * QSCALE;
          Qbuf[((b * 16 + (o >> 4)) * 512 + p) * 16 + (o & 15)] = f2bf(v);
        }
      }
  } else if (bx < 4096) {  // ---- nodes_c role
    int ix = bx - 3072;
    int jt = ix & 3, mt = (ix >> 2) & 7, b = ix >> 5;
    f32x4 acc[2][2];
    proj_core_f32(nodes + ((long)b * 512 + mt * 64) * 256, WcT_bf + jt * 64 * 256, Ws, acc);
    for (int ms = 0; ms < 2; ++ms)
      for (int fj = 0; fj < 2; ++fj) {
        int j = jt * 64 + wj + fj * 16 + lr;
        for (int r = 0; r < 4; ++r) {
          int n = mt * 64 + wm + ms * 16 + qq * 4 + r;
          nodes_c[swz_off((u32)(b * 512 + n), (u32)j)] = f2bf(acc[ms][fj][r]);
        }
      }
  } else {  // ---- bias_n role: one block per b
    int b = bx - 4096;
    const float4* r0 = (const float4*)(nodes + ((long)b * 512 + t) * 256);
    const float4* r1 = (const float4*)(nodes + ((long)b * 512 + t + 256) * 256);
    const float4* wb4 = (const float4*)Wcb;
    float s0 = 0.f, s1 = 0.f;
#pragma unroll 4
    for (int i = 0; i < 64; ++i) {
      float4 wb = wb4[i];
      float4 a0 = r0[i];
      float4 a1 = r1[i];
      s0 += a0.x * wb.x + a0.y * wb.y + a0.z * wb.z + a0.w * wb.w;
      s1 += a1.x * wb.x + a1.y * wb.y + a1.z * wb.z + a1.w * wb.w;
    }
    bias_n[b * 512 + t] = s0;
    bias_n[b * 512 + t + 256] = s1;
  }
}

// ---------------------------------------------------------------------------
// K2 attn: one (bh, half) per block; staged K/V reused across 2 p-tiles of
// 128. S^T = K*Q^T via mfma_32x32x16; register P-relayout; exp2 path.
// bx = pt*512 + bh so both pt-blocks of a bh share an XCD.
// ---------------------------------------------------------------------------
__global__ __launch_bounds__(256) void attn_kernel(
    const u16* __restrict__ Qb, const u16* __restrict__ Kb,
    const u16* __restrict__ Vb, u16* __restrict__ Ob) {
  __shared__ __attribute__((aligned(16))) u16 Ks[8192];
  __shared__ __attribute__((aligned(16))) u16 Vt[8192];
  int bx = blockIdx.x;
  int pt = bx >> 9, bh = bx & 511;
  int t = threadIdx.x, lane = t & 63, w = t >> 6;
  int lo5 = lane & 31, hi = lane >> 5;
  int vd = lane & 15;
  for (int c = 0; c < 4; ++c) {
    __builtin_amdgcn_global_load_lds(AS1U(Kb + bh * 8192 + c * 2048 + t * 8),
                                     AS3U(Ks + c * 2048 + w * 512), 16, 0, 0);
    __builtin_amdgcn_global_load_lds(AS1U(Vb + bh * 8192 + c * 2048 + t * 8),
                                     AS3U(Vt + c * 2048 + w * 512), 16, 0, 0);
  }
  __syncthreads();
  int b = bh >> 4, h = bh & 15;
  for (int pp = 0; pp < 2; ++pp) {
    int p0 = pt * 256 + pp * 128 + w * 32;
    short8 qf = *(const short8*)(Qb + bh * 8192 + (p0 + lo5) * 16 + hi * 8);
    f32x16 oacc = {};
    float lsum = 0.f;
    for (int it = 0; it < 16; ++it) {
      short8 kf = *(const short8*)(Ks + it * 512 + lane * 8);
      f32x16 st = __builtin_amdgcn_mfma_f32_32x32x16_bf16(kf, qf, (f32x16){}, 0, 0, 0);
      float ev[16];
      float ls = 0.f;
#pragma unroll
      for (int r = 0; r < 16; ++r) ev[r] = __builtin_amdgcn_exp2f(st[r]);
#pragma unroll
      for (int r = 0; r < 16; ++r) ls += ev[r];
      lsum += ls;
      u32 pk[8], pd[8];
#pragma unroll
      for (int q = 0; q < 8; ++q) pk[q] = pack_bf(ev[2 * q], ev[2 * q + 1]);
#pragma unroll
      for (int q = 0; q < 8; ++q) pd[q] = (u32)__shfl_xor((int)pk[q], 32, 64);
      bool h1 = (hi != 0);
      u32x4 a1u = {h1 ? pd[2] : pk[0], h1 ? pd[3] : pk[1],
                   h1 ? pk[2] : pd[0], h1 ? pk[3] : pd[1]};
      u32x4 a2u = {h1 ? pd[6] : pk[4], h1 ? pd[7] : pk[5],
                   h1 ? pk[6] : pd[4], h1 ? pk[7] : pd[5]};
      short8 A1 = __builtin_bit_cast(short8, a1u);
      short8 A2 = __builtin_bit_cast(short8, a2u);
      int G1 = it * 4 + hi, G2 = G1 + 2;
      short8 v1 = *(const short8*)(Vt + vd * 512 + (((G1 & ~7) | ((G1 & 7) ^ (vd & 7)))) * 8);
      short8 v2 = *(const short8*)(Vt + vd * 512 + (((G2 & ~7) | ((G2 & 7) ^ (vd & 7)))) * 8);
      oacc = __builtin_amdgcn_mfma_f32_32x32x16_bf16(A1, v1, oacc, 0, 0, 0);
      oacc = __builtin_amdgcn_mfma_f32_32x32x16_bf16(A2, v2, oacc, 0, 0, 0);
    }
    lsum += __shfl_xor(lsum, 32, 64);
    float inv = __builtin_amdgcn_rcpf(lsum);
    float iv[16];
#pragma unroll
    for (int r = 0; r < 16; ++r) {
      int pl = (r & 3) + 8 * (r >> 2) + 4 * hi;
      iv[r] = __shfl(inv, pl, 64);
    }
    if (lo5 < 16) {
#pragma unroll
      for (int r = 0; r < 16; ++r) {
        int pl = (r & 3) + 8 * (r >> 2) + 4 * hi;
        u32 row = (u32)(b * 512 + p0 + pl);
        u32 k = (u32)(h * 16 + lo5);
        Ob[swz_off(row, k)] = f2bf(oacc[r] * iv[r]);
      }
    }
  }
}

// ---------------------------------------------------------------------------
// K3 s2: score2 = O @ nodes_c^T (+bias_n), then topk/penalty/tanh/ninf/
// softmax. b = bx&31 -> all 32 ptile-blocks of b on XCD b%8 (nodes_c[b],
// O[b] L2-local). cdist/ninf/bias loads issued before the GEMM loop.
// ---------------------------------------------------------------------------
__global__ __launch_bounds__(256) void s2_fused_kernel(
    const u16* __restrict__ Obuf, const u16* __restrict__ nodes_c,
    const float* __restrict__ bias_n, const float* __restrict__ cdist,
    const float* __restrict__ ninf, float* __restrict__ out) {
  __shared__ float lg[16][516];
  int bx = blockIdx.x;
  int b = bx & 31, ptile = bx >> 5;
  int t = threadIdx.x, lane = t & 63, w = t >> 6;
  int qq = lane >> 4, lr = lane & 15;
  // A-fragments (16 rows of O x 256 k), swizzled global
  short8 afr[8];
  const u16* Abase = Obuf + (u32)(b * 512 + ptile * 16) * 256;
#pragma unroll
  for (int kt = 0; kt < 8; ++kt) {
    int g = kt * 4 + qq;
    int pos = (g & ~7) | ((g & 7) ^ (lr & 7));
    afr[kt] = *(const short8*)(Abase + lr * 256 + pos * 8);
  }
  // issue phase-2 streams early (overlap with GEMM)
  long grow0 = (long)b * 512 + ptile * 16 + w * 4;
  u32 u[4][8];
#pragma unroll
  for (int rr = 0; rr < 4; ++rr) {
    const u32* du = (const u32*)(cdist + (grow0 + rr) * 512);
#pragma unroll
    for (int i = 0; i < 8; ++i) u[rr][i] = du[i * 64 + lane];
  }
  float bn[8];
#pragma unroll
  for (int i = 0; i < 8; ++i) bn[i] = bias_n[b * 512 + i * 64 + lane];
  // GEMM: wave w owns cols [w*128, w*128+128), B direct from global (L2-local)
  const u16* Bbase = nodes_c + (u32)b * 512 * 256;
#pragma unroll
  for (int nti = 0; nti < 8; ++nti) {
    int nt = w * 8 + nti;
    f32x4 acc = {0.f, 0.f, 0.f, 0.f};
#pragma unroll
    for (int kt = 0; kt < 8; ++kt) {
      int g = kt * 4 + qq;
      int pos = (g & ~7) | ((g & 7) ^ (lr & 7));
      short8 bfv = *(const short8*)(Bbase + (nt * 16 + lr) * 256 + pos * 8);
      acc = __builtin_amdgcn_mfma_f32_16x16x32_bf16(afr[kt], bfv, acc, 0, 0, 0);
    }
#pragma unroll
    for (int r = 0; r < 4; ++r) lg[qq * 4 + r][nt * 16 + lr] = acc[r];
  }
  float nf[4][8];
#pragma unroll
  for (int rr = 0; rr < 4; ++rr) {
    const float* nr = ninf + (grow0 + rr) * 512;
#pragma unroll
    for (int i = 0; i < 8; ++i) nf[rr][i] = nr[i * 64 + lane];
  }
  __syncthreads();
  // interleaved early-exit binary searches (exact lax.top_k semantics)
  u32 lo[4] = {0u, 0u, 0u, 0u};
  u32 hi[4] = {0x3F800000u, 0x3F800000u, 0x3F800000u, 0x3F800000u};
  u32 T[4];
  u32 donemask = 0, simple = 0;
  for (int iter = 0; iter < 32; ++iter) {
    if (donemask == 15u) break;
#pragma unroll
    for (int rr = 0; rr < 4; ++rr) {
      if (donemask & (1u << rr)) continue;  // wave-uniform
      u32 mid = lo[rr] + ((hi[rr] - lo[rr]) >> 1);
      int cnt = 0;
#pragma unroll
      for (int i = 0; i < 8; ++i) cnt += __popcll(__ballot(u[rr][i] <= mid));
      if (cnt == 100) {
        T[rr] = mid; donemask |= 1u << rr; simple |= 1u << rr;
      } else {
        if (cnt > 100) hi[rr] = mid; else lo[rr] = mid + 1;
        if (lo[rr] >= hi[rr]) { T[rr] = lo[rr]; donemask |= 1u << rr; }
      }
    }
  }
  u64 lm = (1ull << lane) - 1ull;
#pragma unroll
  for (int rr = 0; rr < 4; ++rr) {
    long grow = grow0 + rr;
    bool smp = (simple >> rr) & 1u;  // wave-uniform
    u32 Tr = T[rr];
    int quota = 0, eqacc = 0;
    if (!smp) {
      int cl = 0;
#pragma unroll
      for (int i = 0; i < 8; ++i) cl += __popcll(__ballot(u[rr][i] < Tr));
      quota = 100 - cl;
    }
    float ex[8];
    float s = 0.f;
#pragma unroll
    for (int i = 0; i < 8; ++i) {
      bool sel;
      if (smp) {
        sel = (u[rr][i] <= Tr);
      } else {
        u64 e = __ballot(u[rr][i] == Tr);
        sel = (u[rr][i] < Tr) ||
              ((u[rr][i] == Tr) && ((eqacc + __popcll(e & lm)) < quota));
        eqacc += __popcll(e);
      }
      float dvv = __builtin_bit_cast(float, u[rr][i]);
      float x = (lg[w * 4 + rr][i * 64 + lane] + bn[i]) * 0.0625f +
                (sel ? -dvv * INV_SQRT2 : 1.0f);
      float lgt = 10.0f * fast_tanh(x) + nf[rr][i];
      ex[i] = __builtin_amdgcn_exp2f(lgt * LOG2E);
      s += ex[i];
    }
    for (int m = 1; m < 64; m <<= 1) s += __shfl_xor(s, m, 64);
    float inv = 1.0f / s;
    float* orow = out + grow * 512;
#pragma unroll
    for (int i = 0; i < 8; ++i) orow[i * 64 + lane] = ex[i] * inv;
  }
}

// ---------------------------------------------------------------------------
extern "C" void kernel_launch(void* const* d_in, const int* in_sizes, int n_in,
                              void* d_out, int out_size, void* d_ws, size_t ws_size,
                              hipStream_t stream) {
  const float* nodes = (const float*)d_in[0];
  const float* last  = (const float*)d_in[1];
  const float* loadv = (const float*)d_in[2];
  const float* cdist = (const float*)d_in[3];
  const float* ninf  = (const float*)d_in[6];
  const float* Wq    = (const float*)d_in[7];
  const float* Wk    = (const float*)d_in[8];
  const float* Wv    = (const float*)d_in[9];
  const float* Wc    = (const float*)d_in[10];
  const float* Wcb   = (const float*)d_in[11];

  char* ws = (char*)d_ws;
  u16* Kbuf     = (u16*)(ws + 0);
  u16* Vbuf     = (u16*)(ws + 8388608);
  u16* Qbuf     = (u16*)(ws + 16777216);
  u16* Obuf     = (u16*)(ws + 25165824);
  u16* nodes_c  = (u16*)(ws + 33554432);
  u16* Wkv_bf   = (u16*)(ws + 41943040);
  u16* Wq_bf    = (u16*)(ws + 42205184);
  u16* WcT_bf   = (u16*)(ws + 42336256);
  float* wq_lc  = (float*)(ws + 42467328);
  float* bias_n = (float*)(ws + 42468352);

  float* out = (float*)d_out;

  prep_w_kernel<<<129, 256, 0, stream>>>(Wk, Wv, Wq, Wc,
                                         Wkv_bf, Wq_bf, WcT_bf, wq_lc);
  fused_proj_kernel<<<4128, 256, 0, stream>>>(nodes, last, loadv, Wcb,
                                              Wkv_bf, Wq_bf, WcT_bf, wq_lc,
                                              Kbuf, Vbuf, Qbuf, nodes_c, bias_n);
  attn_kernel<<<1024, 256, 0, stream>>>(Qbuf, Kbuf, Vbuf, Obuf);
  s2_fused_kernel<<<1024, 256, 0, stream>>>(Obuf, nodes_c, bias_n, cdist, ninf, out);
}

// Round 6
// 304.664 us; speedup vs baseline: 1.0414x; 1.0414x over previous
//
#include <hip/hip_runtime.h>

// CVRP decoder v6, MI355X. 4 kernels:
//  K0 prep_w: Wkv/Wq/Wc^T -> bf16 swizzled (+ wq_last col)
//  K1 fused_proj: A-STATIONARY. Block stages one 64x256 A-tile (inline
//     fp32->bf16->LDS, source read once), then loops all j-tiles with W
//     streamed from L2. Roles: nodes (Wkv+WcT -> K,V,nodes_c) | last (Wq ->
//     Q) | bias_n.
//  K2 attn (32x32 MFMA, register P-relayout)
//  K3 s2: 8-row blocks (16.5KB LDS -> 8 blocks/CU), GEMM + topk + tanh +
//     softmax, XCD-affinity swizzle.
// Swizzle: (row,k): granule g=k>>3 stored at pos=(g&~7)|((g&7)^(row&7)).

typedef unsigned short u16;
typedef unsigned int u32;
typedef unsigned long long u64;
typedef __attribute__((ext_vector_type(8))) short short8;
typedef __attribute__((ext_vector_type(4))) float f32x4;
typedef __attribute__((ext_vector_type(16))) float f32x16;
typedef __attribute__((ext_vector_type(4))) u32 u32x4;
typedef __attribute__((ext_vector_type(8))) u16 u16x8;

#define AS1U(p) ((const __attribute__((address_space(1))) u32*)(p))
#define AS3U(p) ((__attribute__((address_space(3))) u32*)(p))

#define QSCALE (0.25f * 1.44269504088896340736f)  // 1/sqrt(D) * log2(e)
#define LOG2E 1.44269504088896340736f
#define INV_SQRT2 0.70710678118654752440f

__device__ __forceinline__ u16 f2bf(float f) {
  u32 u = __builtin_bit_cast(u32, f);
  return (u16)((u + 0x7FFFu + ((u >> 16) & 1u)) >> 16);  // RNE
}

__device__ __forceinline__ u32 pack_bf(float a, float b) {
  u32 ua = __builtin_bit_cast(u32, a), ub = __builtin_bit_cast(u32, b);
  ua = ua + 0x7FFFu + ((ua >> 16) & 1u);
  ub = ub + 0x7FFFu + ((ub >> 16) & 1u);
  return __builtin_amdgcn_perm(ub, ua, 0x07060302u);
}

__device__ __forceinline__ short8 packf8(float4 a, float4 b) {
  u32x4 r = {pack_bf(a.x, a.y), pack_bf(a.z, a.w),
             pack_bf(b.x, b.y), pack_bf(b.z, b.w)};
  return __builtin_bit_cast(short8, r);
}

__device__ __forceinline__ u32 swz_off(u32 row, u32 k) {  // half-index
  u32 g = k >> 3;
  u32 pos = (g & ~7u) | ((g & 7u) ^ (row & 7u));
  return row * 256u + pos * 8u + (k & 7u);
}

__device__ __forceinline__ float fast_tanh(float x) {
  float e = __builtin_amdgcn_exp2f(x * (2.0f * LOG2E));
  return 1.0f - 2.0f * __builtin_amdgcn_rcpf(e + 1.0f);
}

// ---------------------------------------------------------------------------
// K0: weight prep. Wkv (512x256), Wq main (256x256, src stride 257),
// Wc^T (256x256 gather-transpose), wq_last column. All bf16 swizzled rows.
// ---------------------------------------------------------------------------
__global__ __launch_bounds__(256) void prep_w_kernel(
    const float* __restrict__ Wk, const float* __restrict__ Wv,
    const float* __restrict__ Wq, const float* __restrict__ Wc,
    u16* __restrict__ Wkv_bf, u16* __restrict__ Wq_bf,
    u16* __restrict__ WcT_bf, float* __restrict__ wq_last) {
  int i = blockIdx.x * 256 + threadIdx.x;
  if (i < 16384) {  // Wkv
    u32 row = (u32)i >> 5, g = (u32)i & 31;
    const float* src = (row < 256) ? (Wk + row * 256 + g * 8)
                                   : (Wv + (row - 256) * 256 + g * 8);
    u16x8 o;
    for (int q = 0; q < 8; ++q) o[q] = f2bf(src[q]);
    u32 pos = (g & ~7u) | ((g & 7u) ^ (row & 7u));
    *(u16x8*)(Wkv_bf + row * 256 + pos * 8) = o;
  } else if (i < 24576) {  // Wq main
    int j = i - 16384;
    u32 row = (u32)j >> 5, g = (u32)j & 31;
    const float* src = Wq + row * 257 + g * 8;
    u16x8 o;
    for (int q = 0; q < 8; ++q) o[q] = f2bf(src[q]);
    u32 pos = (g & ~7u) | ((g & 7u) ^ (row & 7u));
    *(u16x8*)(Wq_bf + row * 256 + pos * 8) = o;
  } else if (i < 32768) {  // Wc^T: W'[j][i] = Wc[i][j]
    int j = i - 24576;
    u32 row = (u32)j >> 5, g = (u32)j & 31;  // row = output col j
    u16x8 o;
    for (int q = 0; q < 8; ++q) o[q] = f2bf(Wc[(g * 8 + q) * 256 + row]);
    u32 pos = (g & ~7u) | ((g & 7u) ^ (row & 7u));
    *(u16x8*)(WcT_bf + row * 256 + pos * 8) = o;
  } else if (i < 33024) {  // Wq last column (fp32)
    int o = i - 32768;
    wq_last[o] = Wq[o * 257 + 256];
  }
}

// ---------------------------------------------------------------------------
// K1: A-stationary fused projections.
//   bx in [0,256):   nodes role. b=bx>>3, mt=bx&7. A = nodes[b, mt*64..+64).
//                    12 j-tiles: jt<8 -> Wkv (K/V out), jt>=8 -> WcT (nodes_c).
//   bx in [256,512): q role. A = last tile; 4 j-tiles of Wq -> Qbuf.
//   bx in [512,544): bias_n[b][n] = <Wc_b, nodes[b][n]>.
// A staged once (inline fp32->bf16, swizzled); W-frags direct from L2.
// ---------------------------------------------------------------------------
__global__ __launch_bounds__(256) void fused_proj_kernel(
    const float* __restrict__ nodes, const float* __restrict__ last,
    const float* __restrict__ loadv, const float* __restrict__ Wcb,
    const u16* __restrict__ Wkv_bf, const u16* __restrict__ Wq_bf,
    const u16* __restrict__ WcT_bf, const float* __restrict__ wq_last,
    u16* __restrict__ Kbuf, u16* __restrict__ Vbuf, u16* __restrict__ Qbuf,
    u16* __restrict__ nodes_c, float* __restrict__ bias_n) {
  __shared__ __attribute__((aligned(16))) u16 As[16384];
  int bx = blockIdx.x;
  int t = threadIdx.x, lane = t & 63, w = t >> 6;
  int wm = (w & 1) * 32, wj = (w >> 1) * 32, qq = lane >> 4, lr = lane & 15;
  if (bx < 512) {
    bool isq = (bx >= 256);
    int ix = bx & 255;
    int b = ix >> 3, mt = ix & 7;
    const float* Abase = (isq ? last : nodes) + ((long)b * 512 + mt * 64) * 256;
    // stage A: fp32 -> bf16 swizzled LDS (source read once, coalesced)
#pragma unroll
    for (int i = 0; i < 8; ++i) {
      int flat = i * 2048 + t * 8;           // half-index
      int row = flat >> 8;                   // 0..63
      int g = (flat >> 3) & 31;
      const float4* p = (const float4*)(Abase + row * 256 + g * 8);
      float4 v0 = p[0], v1 = p[1];
      int pos = (g & ~7) | ((g & 7) ^ (row & 7));
      *(short8*)(As + row * 256 + pos * 8) = packf8(v0, v1);
    }
    __syncthreads();
    int njt = isq ? 4 : 12;
    for (int jt = 0; jt < njt; ++jt) {
      const u16* Wt = isq ? (Wq_bf + jt * 64 * 256)
                          : (jt < 8 ? (Wkv_bf + jt * 64 * 256)
                                    : (WcT_bf + (jt - 8) * 64 * 256));
      f32x4 acc[2][2];
      acc[0][0] = (f32x4){0.f, 0.f, 0.f, 0.f};
      acc[0][1] = (f32x4){0.f, 0.f, 0.f, 0.f};
      acc[1][0] = (f32x4){0.f, 0.f, 0.f, 0.f};
      acc[1][1] = (f32x4){0.f, 0.f, 0.f, 0.f};
#pragma unroll
      for (int kt = 0; kt < 8; ++kt) {
        int g = kt * 4 + qq;
        int pos = (g & ~7) | ((g & 7) ^ (lr & 7));
        short8 a0 = *(const short8*)(As + (wm + lr) * 256 + pos * 8);
        short8 a1 = *(const short8*)(As + (wm + 16 + lr) * 256 + pos * 8);
        short8 b0 = *(const short8*)(Wt + (wj + lr) * 256 + pos * 8);
        short8 b1 = *(const short8*)(Wt + (wj + 16 + lr) * 256 + pos * 8);
        acc[0][0] = __builtin_amdgcn_mfma_f32_16x16x32_bf16(a0, b0, acc[0][0], 0, 0, 0);
        acc[0][1] = __builtin_amdgcn_mfma_f32_16x16x32_bf16(a0, b1, acc[0][1], 0, 0, 0);
        acc[1][0] = __builtin_amdgcn_mfma_f32_16x16x32_bf16(a1, b0, acc[1][0], 0, 0, 0);
        acc[1][1] = __builtin_amdgcn_mfma_f32_16x16x32_bf16(a1, b1, acc[1][1], 0, 0, 0);
      }
      if (isq) {
        for (int ms = 0; ms < 2; ++ms)
          for (int fj = 0; fj < 2; ++fj) {
            int o = jt * 64 + wj + fj * 16 + lr;
            float wql = wq_last[o];
            for (int r = 0; r < 4; ++r) {
              int p = mt * 64 + wm + ms * 16 + qq * 4 + r;
              float ld = loadv[b * 512 + p];
              float v = (acc[ms][fj][r] + ld * wql) * QSCALE;
              Qbuf[((b * 16 + (o >> 4)) * 512 + p) * 16 + (o & 15)] = f2bf(v);
            }
          }
      } else if (jt < 8) {
        for (int ms = 0; ms < 2; ++ms)
          for (int fj = 0; fj < 2; ++fj) {
            int j = jt * 64 + wj + fj * 16 + lr;
            for (int r = 0; r < 4; ++r) {
              int n = mt * 64 + wm + ms * 16 + qq * 4 + r;
              u16 val = f2bf(acc[ms][fj][r]);
              if (j < 256) {  // K: [bh][nch32][2][32][8]
                int h = j >> 4, d = j & 15;
                Kbuf[(u32)(b * 16 + h) * 8192 + (u32)(n >> 5) * 512 +
                     (u32)(d >> 3) * 256 + (u32)(n & 31) * 8 + (u32)(d & 7)] = val;
              } else {        // V: [bh][d][n] swizzled on n
                int o = j - 256, h = o >> 4, d = o & 15;
                u32 G = (u32)(n >> 3);
                u32 pos2 = (G & ~7u) | ((G & 7u) ^ ((u32)d & 7u));
                Vbuf[(u32)(b * 16 + h) * 8192 + (u32)d * 512 + pos2 * 8 + (u32)(n & 7)] = val;
              }
            }
          }
      } else {
        for (int ms = 0; ms < 2; ++ms)
          for (int fj = 0; fj < 2; ++fj) {
            int j = (jt - 8) * 64 + wj + fj * 16 + lr;
            for (int r = 0; r < 4; ++r) {
              int n = mt * 64 + wm + ms * 16 + qq * 4 + r;
              nodes_c[swz_off((u32)(b * 512 + n), (u32)j)] = f2bf(acc[ms][fj][r]);
            }
          }
      }
    }
  } else {  // ---- bias_n role
    int b = bx - 512;
    const float4* r0 = (const float4*)(nodes + ((long)b * 512 + t) * 256);
    const float4* r1 = (const float4*)(nodes + ((long)b * 512 + t + 256) * 256);
    const float4* wb4 = (const float4*)Wcb;
    float s0 = 0.f, s1 = 0.f;
#pragma unroll 4
    for (int i = 0; i < 64; ++i) {
      float4 wb = wb4[i];
      float4 a0 = r0[i];
      float4 a1 = r1[i];
      s0 += a0.x * wb.x + a0.y * wb.y + a0.z * wb.z + a0.w * wb.w;
      s1 += a1.x * wb.x + a1.y * wb.y + a1.z * wb.z + a1.w * wb.w;
    }
    bias_n[b * 512 + t] = s0;
    bias_n[b * 512 + t + 256] = s1;
  }
}

// ---------------------------------------------------------------------------
// K2 attn: one (bh, half) per block; staged K/V reused across 2 p-tiles of
// 128. S^T = K*Q^T via mfma_32x32x16; register P-relayout; exp2 path.
// ---------------------------------------------------------------------------
__global__ __launch_bounds__(256) void attn_kernel(
    const u16* __restrict__ Qb, const u16* __restrict__ Kb,
    const u16* __restrict__ Vb, u16* __restrict__ Ob) {
  __shared__ __attribute__((aligned(16))) u16 Ks[8192];
  __shared__ __attribute__((aligned(16))) u16 Vt[8192];
  int bx = blockIdx.x;
  int pt = bx >> 9, bh = bx & 511;
  int t = threadIdx.x, lane = t & 63, w = t >> 6;
  int lo5 = lane & 31, hi = lane >> 5;
  int vd = lane & 15;
  for (int c = 0; c < 4; ++c) {
    __builtin_amdgcn_global_load_lds(AS1U(Kb + bh * 8192 + c * 2048 + t * 8),
                                     AS3U(Ks + c * 2048 + w * 512), 16, 0, 0);
    __builtin_amdgcn_global_load_lds(AS1U(Vb + bh * 8192 + c * 2048 + t * 8),
                                     AS3U(Vt + c * 2048 + w * 512), 16, 0, 0);
  }
  __syncthreads();
  int b = bh >> 4, h = bh & 15;
  for (int pp = 0; pp < 2; ++pp) {
    int p0 = pt * 256 + pp * 128 + w * 32;
    short8 qf = *(const short8*)(Qb + bh * 8192 + (p0 + lo5) * 16 + hi * 8);
    f32x16 oacc = {};
    float lsum = 0.f;
    for (int it = 0; it < 16; ++it) {
      short8 kf = *(const short8*)(Ks + it * 512 + lane * 8);
      f32x16 st = __builtin_amdgcn_mfma_f32_32x32x16_bf16(kf, qf, (f32x16){}, 0, 0, 0);
      float ev[16];
      float ls = 0.f;
#pragma unroll
      for (int r = 0; r < 16; ++r) ev[r] = __builtin_amdgcn_exp2f(st[r]);
#pragma unroll
      for (int r = 0; r < 16; ++r) ls += ev[r];
      lsum += ls;
      u32 pk[8], pd[8];
#pragma unroll
      for (int q = 0; q < 8; ++q) pk[q] = pack_bf(ev[2 * q], ev[2 * q + 1]);
#pragma unroll
      for (int q = 0; q < 8; ++q) pd[q] = (u32)__shfl_xor((int)pk[q], 32, 64);
      bool h1 = (hi != 0);
      u32x4 a1u = {h1 ? pd[2] : pk[0], h1 ? pd[3] : pk[1],
                   h1 ? pk[2] : pd[0], h1 ? pk[3] : pd[1]};
      u32x4 a2u = {h1 ? pd[6] : pk[4], h1 ? pd[7] : pk[5],
                   h1 ? pk[6] : pd[4], h1 ? pk[7] : pd[5]};
      short8 A1 = __builtin_bit_cast(short8, a1u);
      short8 A2 = __builtin_bit_cast(short8, a2u);
      int G1 = it * 4 + hi, G2 = G1 + 2;
      short8 v1 = *(const short8*)(Vt + vd * 512 + (((G1 & ~7) | ((G1 & 7) ^ (vd & 7)))) * 8);
      short8 v2 = *(const short8*)(Vt + vd * 512 + (((G2 & ~7) | ((G2 & 7) ^ (vd & 7)))) * 8);
      oacc = __builtin_amdgcn_mfma_f32_32x32x16_bf16(A1, v1, oacc, 0, 0, 0);
      oacc = __builtin_amdgcn_mfma_f32_32x32x16_bf16(A2, v2, oacc, 0, 0, 0);
    }
    lsum += __shfl_xor(lsum, 32, 64);
    float inv = __builtin_amdgcn_rcpf(lsum);
    float iv[16];
#pragma unroll
    for (int r = 0; r < 16; ++r) {
      int pl = (r & 3) + 8 * (r >> 2) + 4 * hi;
      iv[r] = __shfl(inv, pl, 64);
    }
    if (lo5 < 16) {
#pragma unroll
      for (int r = 0; r < 16; ++r) {
        int pl = (r & 3) + 8 * (r >> 2) + 4 * hi;
        u32 row = (u32)(b * 512 + p0 + pl);
        u32 k = (u32)(h * 16 + lo5);
        Ob[swz_off(row, k)] = f2bf(oacc[r] * iv[r]);
      }
    }
  }
}

// ---------------------------------------------------------------------------
// K3 s2: 8-row blocks. score2 = O @ nodes_c^T (+bias_n) -> lg (16.5KB LDS,
// 8 blocks/CU), then topk/penalty/tanh/ninf/softmax (2 rows per wave).
// b = bx&31 -> XCD affinity for nodes_c[b]/O[b].
// ---------------------------------------------------------------------------
__global__ __launch_bounds__(256) void s2_fused_kernel(
    const u16* __restrict__ Obuf, const u16* __restrict__ nodes_c,
    const float* __restrict__ bias_n, const float* __restrict__ cdist,
    const float* __restrict__ ninf, float* __restrict__ out) {
  __shared__ float lg[8][516];
  int bx = blockIdx.x;
  int b = bx & 31, ptile = bx >> 5;  // ptile 0..63, 8 rows each
  int t = threadIdx.x, lane = t & 63, w = t >> 6;
  int qq = lane >> 4, lr = lane & 15;
  // A-fragments: MFMA needs 16 rows; rows 8..15 are neighbors' rows
  // (clamped at the array end) — their outputs are discarded.
  short8 afr[8];
  int arow = ptile * 8 + lr;
  if (arow > 511) arow = 511;
  const u16* Arow = Obuf + ((u32)(b * 512) + (u32)arow) * 256;
#pragma unroll
  for (int kt = 0; kt < 8; ++kt) {
    int g = kt * 4 + qq;
    int pos = (g & ~7) | ((g & 7) ^ (arow & 7));
    afr[kt] = *(const short8*)(Arow + pos * 8);
  }
  // hoist phase-2 streams (overlap with GEMM)
  long grow0 = (long)b * 512 + ptile * 8 + w * 2;
  u32 u[2][8];
#pragma unroll
  for (int rr = 0; rr < 2; ++rr) {
    const u32* du = (const u32*)(cdist + (grow0 + rr) * 512);
#pragma unroll
    for (int i = 0; i < 8; ++i) u[rr][i] = du[i * 64 + lane];
  }
  float nf[2][8];
#pragma unroll
  for (int rr = 0; rr < 2; ++rr) {
    const float* nr = ninf + (grow0 + rr) * 512;
#pragma unroll
    for (int i = 0; i < 8; ++i) nf[rr][i] = nr[i * 64 + lane];
  }
  float bn[8];
#pragma unroll
  for (int i = 0; i < 8; ++i) bn[i] = bias_n[b * 512 + i * 64 + lane];
  // GEMM: wave w owns cols [w*128, w*128+128)
  const u16* Bbase = nodes_c + (u32)b * 512 * 256;
#pragma unroll
  for (int nti = 0; nti < 8; ++nti) {
    int nt = w * 8 + nti;
    f32x4 acc = {0.f, 0.f, 0.f, 0.f};
#pragma unroll
    for (int kt = 0; kt < 8; ++kt) {
      int g = kt * 4 + qq;
      int pos = (g & ~7) | ((g & 7) ^ (lr & 7));
      short8 bfv = *(const short8*)(Bbase + (nt * 16 + lr) * 256 + pos * 8);
      acc = __builtin_amdgcn_mfma_f32_16x16x32_bf16(afr[kt], bfv, acc, 0, 0, 0);
    }
    if (qq < 2) {  // rows 0..7 valid
#pragma unroll
      for (int r = 0; r < 4; ++r) lg[qq * 4 + r][nt * 16 + lr] = acc[r];
    }
  }
  __syncthreads();
  // interleaved early-exit binary searches (exact lax.top_k semantics)
  u32 lo[2] = {0u, 0u};
  u32 hi[2] = {0x3F800000u, 0x3F800000u};
  u32 T[2];
  u32 donemask = 0, simple = 0;
  for (int iter = 0; iter < 32; ++iter) {
    if (donemask == 3u) break;
#pragma unroll
    for (int rr = 0; rr < 2; ++rr) {
      if (donemask & (1u << rr)) continue;  // wave-uniform
      u32 mid = lo[rr] + ((hi[rr] - lo[rr]) >> 1);
      int cnt = 0;
#pragma unroll
      for (int i = 0; i < 8; ++i) cnt += __popcll(__ballot(u[rr][i] <= mid));
      if (cnt == 100) {
        T[rr] = mid; donemask |= 1u << rr; simple |= 1u << rr;
      } else {
        if (cnt > 100) hi[rr] = mid; else lo[rr] = mid + 1;
        if (lo[rr] >= hi[rr]) { T[rr] = lo[rr]; donemask |= 1u << rr; }
      }
    }
  }
  u64 lm = (1ull << lane) - 1ull;
#pragma unroll
  for (int rr = 0; rr < 2; ++rr) {
    long grow = grow0 + rr;
    bool smp = (simple >> rr) & 1u;  // wave-uniform
    u32 Tr = T[rr];
    int quota = 0, eqacc = 0;
    if (!smp) {
      int cl = 0;
#pragma unroll
      for (int i = 0; i < 8; ++i) cl += __popcll(__ballot(u[rr][i] < Tr));
      quota = 100 - cl;
    }
    float ex[8];
    float s = 0.f;
#pragma unroll
    for (int i = 0; i < 8; ++i) {
      bool sel;
      if (smp) {
        sel = (u[rr][i] <= Tr);
      } else {
        u64 e = __ballot(u[rr][i] == Tr);
        sel = (u[rr][i] < Tr) ||
              ((u[rr][i] == Tr) && ((eqacc + __popcll(e & lm)) < quota));
        eqacc += __popcll(e);
      }
      float dvv = __builtin_bit_cast(float, u[rr][i]);
      float x = (lg[w * 2 + rr][i * 64 + lane] + bn[i]) * 0.0625f +
                (sel ? -dvv * INV_SQRT2 : 1.0f);
      float lgt = 10.0f * fast_tanh(x) + nf[rr][i];
      ex[i] = __builtin_amdgcn_exp2f(lgt * LOG2E);
      s += ex[i];
    }
    for (int m = 1; m < 64; m <<= 1) s += __shfl_xor(s, m, 64);
    float inv = 1.0f / s;
    float* orow = out + grow * 512;
#pragma unroll
    for (int i = 0; i < 8; ++i) orow[i * 64 + lane] = ex[i] * inv;
  }
}

// ---------------------------------------------------------------------------
extern "C" void kernel_launch(void* const* d_in, const int* in_sizes, int n_in,
                              void* d_out, int out_size, void* d_ws, size_t ws_size,
                              hipStream_t stream) {
  const float* nodes = (const float*)d_in[0];
  const float* last  = (const float*)d_in[1];
  const float* loadv = (const float*)d_in[2];
  const float* cdist = (const float*)d_in[3];
  const float* ninf  = (const float*)d_in[6];
  const float* Wq    = (const float*)d_in[7];
  const float* Wk    = (const float*)d_in[8];
  const float* Wv    = (const float*)d_in[9];
  const float* Wc    = (const float*)d_in[10];
  const float* Wcb   = (const float*)d_in[11];

  char* ws = (char*)d_ws;
  u16* Kbuf     = (u16*)(ws + 0);
  u16* Vbuf     = (u16*)(ws + 8388608);
  u16* Qbuf     = (u16*)(ws + 16777216);
  u16* Obuf     = (u16*)(ws + 25165824);
  u16* nodes_c  = (u16*)(ws + 33554432);
  u16* Wkv_bf   = (u16*)(ws + 41943040);
  u16* Wq_bf    = (u16*)(ws + 42205184);
  u16* WcT_bf   = (u16*)(ws + 42336256);
  float* wq_lc  = (float*)(ws + 42467328);
  float* bias_n = (float*)(ws + 42468352);

  float* out = (float*)d_out;

  prep_w_kernel<<<129, 256, 0, stream>>>(Wk, Wv, Wq, Wc,
                                         Wkv_bf, Wq_bf, WcT_bf, wq_lc);
  fused_proj_kernel<<<544, 256, 0, stream>>>(nodes, last, loadv, Wcb,
                                             Wkv_bf, Wq_bf, WcT_bf, wq_lc,
                                             Kbuf, Vbuf, Qbuf, nodes_c, bias_n);
  attn_kernel<<<1024, 256, 0, stream>>>(Qbuf, Kbuf, Vbuf, Obuf);
  s2_fused_kernel<<<2048, 256, 0, stream>>>(Obuf, nodes_c, bias_n, cdist, ninf, out);
}